// Round 8
// baseline (7955.676 us; speedup 1.0000x reference)
//
#include <hip/hip_runtime.h>
#include <hip/hip_bf16.h>

typedef __hip_bfloat16 bf16;
typedef __attribute__((ext_vector_type(8))) short short8;
typedef __attribute__((ext_vector_type(4))) float f32x4;

__device__ __forceinline__ float b2f(bf16 v){ return __bfloat162float(v); }
__device__ __forceinline__ bf16 f2b(float v){ return __float2bfloat16(v); }
__device__ __forceinline__ float ldf(const bf16* p){ return __bfloat162float(*p); }

__device__ __forceinline__ unsigned short bfbits(float v){
  union{ bf16 h; unsigned short u; } t; t.h = f2b(v); return t.u;
}
__device__ __forceinline__ float bs2f(short s){
  union{ unsigned u; float f; } t; t.u = ((unsigned)(unsigned short)s) << 16; return t.f;
}
__device__ __forceinline__ void store_bf16x2(bf16* p, float a, float b){
  unsigned pk = ((unsigned)bfbits(b) << 16) | (unsigned)bfbits(a);
  *reinterpret_cast<unsigned*>(p) = pk;
}

// ---------------- weight repacks ----------------
// w[Cout][Cin][KK] f32 -> o[KK][Cin][Cout] f32  (enc0 / proj)
__global__ void repack_tco(const float* __restrict__ w, float* __restrict__ o,
                           int Cout, int Cin, int KK){
  int i = blockIdx.x*256 + threadIdx.x;
  int total = Cout*Cin*KK;
  if (i >= total) return;
  int co = i / (Cin*KK);
  int r  = i - co*(Cin*KK);
  int ci = r / KK;
  int t  = r - ci*KK;
  o[((size_t)t*Cin + ci)*Cout + co] = w[i];
}

// w[Cout][Cin][KK] f32 -> o[Cin][KK][Cout] f32  (out conv: [ci][tap][co])
__global__ void repack_cto(const float* __restrict__ w, float* __restrict__ o,
                           int Cout, int Cin, int KK){
  int i = blockIdx.x*256 + threadIdx.x;
  int total = Cout*Cin*KK;
  if (i >= total) return;
  int co = i / (Cin*KK);
  int r  = i - co*(Cin*KK);
  int ci = r / KK;
  int t  = r - ci*KK;
  o[((size_t)ci*KK + t)*Cout + co] = w[i];
}

// w[Cout][Cin][16] f32 -> o[tap][Cout][Cin] bf16  (MFMA A-operand, enc+dec)
__global__ void repack_tcc_bf16(const float* __restrict__ w, short* __restrict__ o,
                                int Cout, int Cin){
  int i = blockIdx.x*256 + threadIdx.x;
  int total = Cout*Cin*16;
  if (i >= total) return;
  int co = i / (Cin*16);
  int r  = i - co*(Cin*16);
  int ci = r >> 4;
  int t  = r & 15;
  o[((size_t)t*Cout + co)*Cin + ci] = (short)bfbits(w[i]);
}

// ---------------- enc0: conv k=4 s=2 p=1, Cin=3, 256->128, Cout=128 ----------------
// thread: 4 outputs along ow, 8 co; weights via wave-uniform loads
__global__ __launch_bounds__(256) void conv_enc0(
    const float* __restrict__ x, const float* __restrict__ wp,  // [tap][ci][co]
    const float* __restrict__ bias, bf16* __restrict__ y)
{
  int t = blockIdx.x*256 + threadIdx.x;     // 4096 threads per (cob,img)
  int oh  = t >> 5;                         // 0..127
  int ow0 = (t & 31) * 4;                   // 0..124
  int co0 = blockIdx.y * 8;
  int n   = blockIdx.z;
  float acc[8][4];
  #pragma unroll
  for (int j=0;j<8;j++){
    float bv = bias[co0+j];
    #pragma unroll
    for (int o=0;o<4;o++) acc[j][o] = bv;
  }
  const float* xn = x + (size_t)n*3*65536;
  #pragma unroll
  for (int ci=0; ci<3; ci++){
    const float* xc = xn + (size_t)ci*65536;
    #pragma unroll
    for (int kh=0; kh<4; kh++){
      int ih = 2*oh - 1 + kh;
      float xv[12];
      if ((unsigned)ih < 256u){
        #pragma unroll
        for (int c2=0; c2<6; c2++){
          int col = 2*ow0 - 2 + 2*c2;
          if (col >= 0 && col < 256){   // col<256: right-edge zero-pad (iw=256) + no OOB read
            float2 v = *(const float2*)(xc + (size_t)ih*256 + col);
            xv[2*c2] = v.x; xv[2*c2+1] = v.y;
          } else { xv[2*c2] = 0.f; xv[2*c2+1] = 0.f; }
        }
      } else {
        #pragma unroll
        for (int k=0;k<12;k++) xv[k] = 0.f;
      }
      #pragma unroll
      for (int kw=0; kw<4; kw++){
        const float* wr = wp + (size_t)((kh*4+kw)*3 + ci)*128 + co0;  // uniform
        #pragma unroll
        for (int j=0;j<8;j++){
          float wf = wr[j];
          #pragma unroll
          for (int o=0;o<4;o++)
            acc[j][o] = fmaf(xv[2*o+kw+1], wf, acc[j][o]);
        }
      }
    }
  }
  #pragma unroll
  for (int j=0;j<8;j++){
    bf16* yp = y + (((size_t)n*128 + co0+j)*128 + oh)*128 + ow0;
    store_bf16x2(yp,   fmaxf(acc[j][0],0.f), fmaxf(acc[j][1],0.f));
    store_bf16x2(yp+2, fmaxf(acc[j][2],0.f), fmaxf(acc[j][3],0.f));
  }
}

// ---------------- enc1/enc2: conv k=4 s=2 p=1 via MFMA, co-shared waves ----------------
// block: 4 waves = SPW col-groups x RW rows; 128 co per block (cs=8).
template<int RW>
__global__ __launch_bounds__(256) void conv_enc_mfma2(
    const short* __restrict__ x, const short* __restrict__ wb,
    const float* __restrict__ bias, short* __restrict__ y,
    int Cin, int Hin, int Win, int Cout)
{
  constexpr int SPW = 4/RW;
  constexpr int IR  = 2*RW + 2;
  constexpr int IC  = 2*SPW*16 + 2;
  constexpr int CIP = 40;
  __shared__ __align__(16) short lds[IR*IC*CIP];

  int tid = threadIdx.x;
  int w = tid >> 6, lane = tid & 63;
  int sw = w % SPW, rw = w / SPW;
  int n15 = lane & 15, quad = lane >> 4;
  int i0 = blockIdx.y;
  int j0 = blockIdx.x * (SPW*16);
  int nct = Cout >> 7;
  int ct = blockIdx.z % nct;
  int nimg = blockIdx.z / nct;
  int co_base = ct*128;
  int Hout = Hin >> 1, Wout = Win >> 1;
  int oh = i0*RW + rw;
  int row_org = 2*i0*RW - 1;
  int col_org = 2*j0 - 1;

  f32x4 acc[8];
  #pragma unroll
  for (int cs=0; cs<8; cs++){
    int cb = co_base + cs*16 + quad*4;
    acc[cs] = f32x4{bias[cb], bias[cb+1], bias[cb+2], bias[cb+3]};
  }

  const short* xn = x + (size_t)nimg*Cin*Hin*Win;
  for (int ci0 = 0; ci0 < Cin; ci0 += 32){
    __syncthreads();
    for (int idx = tid; idx < IR*IC*32; idx += 256){
      int r   = idx / (IC*32);
      int rem = idx - r*(IC*32);
      int ci  = rem / IC;
      int c   = rem - ci*IC;
      int gi = row_org + r, gj = col_org + c;
      short v = 0;
      if ((unsigned)gi < (unsigned)Hin && (unsigned)gj < (unsigned)Win)
        v = xn[((size_t)(ci0+ci)*Hin + gi)*Win + gj];
      lds[(r*IC + c)*CIP + ci] = v;
    }
    __syncthreads();
    #pragma unroll
    for (int kh=0; kh<4; kh++){
      short8 bfr[4];
      #pragma unroll
      for (int kw=0; kw<4; kw++){
        int c = 2*(sw*16 + n15) + kw;
        bfr[kw] = *(const short8*)&lds[((2*rw+kh)*IC + c)*CIP + quad*8];
      }
      #pragma unroll
      for (int kw=0; kw<4; kw++){
        int tap = kh*4 + kw;
        const short* wt = wb + (size_t)(tap*Cout + co_base + n15)*Cin + ci0 + quad*8;
        #pragma unroll
        for (int cs=0; cs<8; cs++){
          short8 af = *(const short8*)(wt + (size_t)cs*16*Cin);
          acc[cs] = __builtin_amdgcn_mfma_f32_16x16x32_bf16(af, bfr[kw], acc[cs], 0,0,0);
        }
      }
    }
  }
  int jj = j0 + sw*16 + n15;
  #pragma unroll
  for (int cs=0; cs<8; cs++){
    #pragma unroll
    for (int r=0; r<4; r++){
      int co = co_base + cs*16 + quad*4 + r;
      float v = fmaxf(acc[cs][r], 0.f);
      y[((size_t)(nimg*Cout + co)*Hout + oh)*Wout + jj] = (short)bfbits(v);
    }
  }
}

// ---------------- proj: 1x1 conv (bf16 in); writes z (f32) to d_out ----------------
template<int CO_BLK>
__global__ void conv1x1(const bf16* __restrict__ x, const float* __restrict__ wp,
                        const float* __restrict__ bias, float* __restrict__ z,
                        int Cin, int HW, int Cout)
{
  int sp = blockIdx.x*256 + threadIdx.x;
  if (sp >= HW) return;
  int n = blockIdx.z, co0 = blockIdx.y*CO_BLK;
  float acc[CO_BLK];
  #pragma unroll
  for (int j=0;j<CO_BLK;j++) acc[j] = bias[co0+j];
  const bf16* xp = x + (size_t)n*Cin*HW + sp;
  for (int ci=0; ci<Cin; ci++){
    float xv = ldf(xp + (size_t)ci*HW);
    #pragma unroll
    for (int j=0;j<CO_BLK;j++)
      acc[j] = fmaf(xv, wp[(size_t)ci*Cout + co0 + j], acc[j]);
  }
  size_t base = ((size_t)n*Cout + co0)*HW + sp;
  #pragma unroll
  for (int j=0;j<CO_BLK;j++)
    z[base + (size_t)j*HW] = acc[j];
}

// ---------------- VQ: per-wave argmin over 1024 codes ----------------
__global__ void vq_argmin(const float* __restrict__ z, const float* __restrict__ cbf,
                          float* __restrict__ zq, bf16* __restrict__ zqst)
{
  __shared__ float lz[4][64];
  int t = threadIdx.x;
  int q = t >> 6, l = t & 63;
  int p = blockIdx.x*4 + q;
  int n = p >> 10, hw = p & 1023;
  size_t zbase = ((size_t)n*64)*1024 + hw;
  float zl = z[zbase + (size_t)l*1024];
  lz[q][l] = zl;
  __syncthreads();
  float best = 3.0e38f; int bi = 0;
  const float* zv = &lz[q][0];
  for (int c = l; c < 1024; c += 64){
    const float4* row = reinterpret_cast<const float4*>(cbf + (size_t)c*64);
    float d = 0.f;
    #pragma unroll
    for (int v4 = 0; v4 < 16; v4++){
      float4 cv = row[v4];
      int j0 = v4*4;
      float d0 = zv[j0+0]-cv.x; d = fmaf(d0,d0,d);
      float d1 = zv[j0+1]-cv.y; d = fmaf(d1,d1,d);
      float d2 = zv[j0+2]-cv.z; d = fmaf(d2,d2,d);
      float d3 = zv[j0+3]-cv.w; d = fmaf(d3,d3,d);
    }
    if (d < best){ best = d; bi = c; }
  }
  #pragma unroll
  for (int off = 32; off > 0; off >>= 1){
    float od = __shfl_down(best, off, 64);
    int   oi = __shfl_down(bi,  off, 64);
    if (od < best || (od == best && oi < bi)){ best = od; bi = oi; }
  }
  bi = __shfl(bi, 0, 64);
  float qv = cbf[(size_t)bi*64 + l];
  size_t oidx = zbase + (size_t)l*1024;
  zq[oidx]   = qv;
  zqst[oidx] = f2b(zl + (qv - zl));
}

// ---------------- decoder: convT k=4 s=2 via MFMA, co-shared waves ----------------
// block: 4 waves = SPW col-groups x RW rows; 64 co per block (cs=4).
template<int RW>
__global__ __launch_bounds__(256) void convT_mfma2(
    const short* __restrict__ x, const short* __restrict__ wb,
    const float* __restrict__ bias, short* __restrict__ y,
    int Cin, int Hin, int Win, int Cout, int relu)
{
  constexpr int SPW = 4/RW;
  constexpr int IR  = RW + 2;
  constexpr int IC  = SPW*16 + 2;
  constexpr int CIP = 40;
  __shared__ __align__(16) short lds[IR*IC*CIP];

  int tid = threadIdx.x;
  int w = tid >> 6, lane = tid & 63;
  int sw = w % SPW, rw = w / SPW;
  int n15 = lane & 15, quad = lane >> 4;
  int i0 = blockIdx.y;
  int j0 = blockIdx.x * (SPW*16);
  int nct = Cout >> 6;
  int ct = blockIdx.z % nct;
  int nimg = blockIdx.z / nct;
  int co_base = ct*64;
  int oh = i0*RW + rw;                // input row of this wave
  int row_org = i0*RW - 1;
  int col_org = j0 - 1;

  f32x4 acc[4][4];   // [cs][parity]
  #pragma unroll
  for (int cs=0; cs<4; cs++){
    int cb = co_base + cs*16 + quad*4;
    f32x4 bv = f32x4{bias[cb], bias[cb+1], bias[cb+2], bias[cb+3]};
    #pragma unroll
    for (int p=0;p<4;p++) acc[cs][p] = bv;
  }

  const short* xn = x + (size_t)nimg*Cin*Hin*Win;
  for (int ci0 = 0; ci0 < Cin; ci0 += 32){
    __syncthreads();
    for (int idx = tid; idx < IR*IC*32; idx += 256){
      int r   = idx / (IC*32);
      int rem = idx - r*(IC*32);
      int ci  = rem / IC;
      int c   = rem - ci*IC;
      int gi = row_org + r, gj = col_org + c;
      short v = 0;
      if ((unsigned)gi < (unsigned)Hin && (unsigned)gj < (unsigned)Win)
        v = xn[((size_t)(ci0+ci)*Hin + gi)*Win + gj];
      lds[(r*IC + c)*CIP + ci] = v;
    }
    __syncthreads();
    short8 bfr[9];
    #pragma unroll
    for (int dr=0; dr<3; dr++)
      #pragma unroll
      for (int dc=0; dc<3; dc++){
        int c = sw*16 + n15 + dc;
        bfr[dr*3+dc] = *(const short8*)&lds[((rw+dr)*IC + c)*CIP + quad*8];
      }
    #pragma unroll
    for (int ph=0; ph<2; ph++)
      #pragma unroll
      for (int pw=0; pw<2; pw++){
        int p = ph*2 + pw;
        #pragma unroll
        for (int u=0; u<2; u++)
          #pragma unroll
          for (int v=0; v<2; v++){
            int tap  = (ph + 2*u)*4 + (pw + 2*v);
            int sidx = (u + ph)*3 + (v + pw);
            const short* wt = wb + (size_t)(tap*Cout + co_base + n15)*Cin + ci0 + quad*8;
            #pragma unroll
            for (int cs=0; cs<4; cs++){
              short8 af = *(const short8*)(wt + (size_t)cs*16*Cin);
              acc[cs][p] = __builtin_amdgcn_mfma_f32_16x16x32_bf16(af, bfr[sidx], acc[cs][p], 0,0,0);
            }
          }
      }
  }
  int Hout = Hin*2, Wout = Win*2;
  int jj = j0 + sw*16 + n15;
  #pragma unroll
  for (int cs=0; cs<4; cs++)
    #pragma unroll
    for (int ph=0; ph<2; ph++)
      #pragma unroll
      for (int r=0; r<4; r++){
        int co = co_base + cs*16 + quad*4 + r;
        float v0 = acc[cs][ph*2+0][r];
        float v1 = acc[cs][ph*2+1][r];
        if (relu){ v0 = fmaxf(v0, 0.f); v1 = fmaxf(v1, 0.f); }
        unsigned pk = ((unsigned)bfbits(v1) << 16) | (unsigned)bfbits(v0);
        *(unsigned*)&y[((size_t)(nimg*Cout + co)*Hout + 2*oh + ph)*Wout + 2*jj] = pk;
      }
}

// ---------------- out conv: 3x3 p=1 s=1, Cout=3, LDS-staged ----------------
// block: 4 rows x 256 cols of one image; ci in 8 groups of 16 staged in LDS
__global__ __launch_bounds__(256) void conv3x3_out2(
    const bf16* __restrict__ x, const float* __restrict__ wct,  // [ci][9][3]
    const float* __restrict__ bias, float* __restrict__ y)
{
  constexpr int PIT = 264;
  __shared__ __align__(16) short xl[6*16*PIT];
  int tid = threadIdx.x;
  int w = tid >> 6, lane = tid & 63;
  int r0 = blockIdx.x * 4;
  int n  = blockIdx.y;
  const short* xn = (const short*)(x + (size_t)n*128*65536);
  float acc[3][4];
  #pragma unroll
  for (int co=0; co<3; co++){
    float bv = bias[co];
    #pragma unroll
    for (int o=0;o<4;o++) acc[co][o] = bv;
  }
  for (int g=0; g<8; g++){
    int cig = g*16;
    __syncthreads();
    for (int idx = tid; idx < 6*16*33; idx += 256){
      int r   = idx / (16*33);
      int rem = idx - r*(16*33);
      int ci  = rem / 33;
      int ch  = rem - ci*33;
      int gi = r0 - 1 + r;
      int gj0 = ch*8 - 4;
      short* dst = &xl[(r*16 + ci)*PIT + ch*8];
      if ((unsigned)gi < 256u && gj0 >= 0 && gj0 + 8 <= 256){
        *(short8*)dst = *(const short8*)(xn + ((size_t)(cig+ci)*256 + gi)*256 + gj0);
      } else {
        #pragma unroll
        for (int k=0;k<8;k++){
          int gj = gj0 + k;
          short v = 0;
          if ((unsigned)gi < 256u && (unsigned)gj < 256u)
            v = xn[((size_t)(cig+ci)*256 + gi)*256 + gj];
          dst[k] = v;
        }
      }
    }
    __syncthreads();
    for (int ci=0; ci<16; ci++){
      const float* wr = wct + (size_t)(cig+ci)*27;   // uniform -> s_load
      float wv[27];
      #pragma unroll
      for (int k=0;k<27;k++) wv[k] = wr[k];
      #pragma unroll
      for (int kh=0; kh<3; kh++){
        const short* xr = &xl[((w + kh)*16 + ci)*PIT + lane*4 + 3];
        float xv[6];
        #pragma unroll
        for (int k=0;k<6;k++) xv[k] = bs2f(xr[k]);
        #pragma unroll
        for (int kw=0;kw<3;kw++)
          #pragma unroll
          for (int co=0;co<3;co++){
            float wf = wv[(kh*3+kw)*3+co];
            #pragma unroll
            for (int o=0;o<4;o++)
              acc[co][o] = fmaf(xv[o+kw], wf, acc[co][o]);
          }
      }
    }
  }
  int oc0 = lane*4;
  #pragma unroll
  for (int co=0; co<3; co++){
    float* yp = y + ((size_t)n*3 + co)*65536 + (size_t)(r0+w)*256 + oc0;
    #pragma unroll
    for (int o=0;o<4;o++) yp[o] = acc[co][o];
  }
}

// ---------------- workspace layout (bytes) ----------------
static const size_t W_WENC0 = 0;           //  24,576 f32 [tap][ci][co]
static const size_t W_WPROJ = 24576;       //  131,072 f32
static const size_t W_WOUT  = 155648;      //  13,824 f32 [ci][tap][co]
static const size_t W_E1B   = 169472;      //  1,048,576 bf16 [tap][co][ci]
static const size_t W_E2B   = 1218048;     //  4,194,304
static const size_t W_D0B   = 5412352;     //  1,048,576
static const size_t W_D1B   = 6460928;     //  4,194,304
static const size_t W_D2B   = 10655232;    //  1,048,576
static const size_t W_BYTES = 11703808;
// per-image activations (lifetime-aliased): A 16MiB (h0/d2), Bg 8MiB (h1/d1),
// C 4MiB (h2/d0), zqs bf16 128KiB
static const size_t PER_IMG = 29491200;

extern "C" void kernel_launch(void* const* d_in, const int* in_sizes, int n_in,
                              void* d_out, int out_size, void* d_ws, size_t ws_size,
                              hipStream_t stream)
{
  const float* x      = (const float*)d_in[0];
  const float* enc_w0 = (const float*)d_in[1];
  const float* enc_b0 = (const float*)d_in[2];
  const float* enc_w1 = (const float*)d_in[3];
  const float* enc_b1 = (const float*)d_in[4];
  const float* enc_w2 = (const float*)d_in[5];
  const float* enc_b2 = (const float*)d_in[6];
  const float* proj_w = (const float*)d_in[7];
  const float* proj_b = (const float*)d_in[8];
  const float* dec_w0 = (const float*)d_in[9];
  const float* dec_b0 = (const float*)d_in[10];
  const float* dec_w1 = (const float*)d_in[11];
  const float* dec_b1 = (const float*)d_in[12];
  const float* dec_w2 = (const float*)d_in[13];
  const float* dec_b2 = (const float*)d_in[14];
  const float* out_w  = (const float*)d_in[15];
  const float* out_b  = (const float*)d_in[16];
  const float* cb     = (const float*)d_in[17];

  float* out    = (float*)d_out;
  float* recon  = out;
  float* z_out  = out + 3145728;
  float* zq_out = out + 4194304;

  char* ws = (char*)d_ws;
  float* wenc0 = (float*)(ws + W_WENC0);
  float* wproj = (float*)(ws + W_WPROJ);
  float* wout  = (float*)(ws + W_WOUT);
  short* we1b  = (short*)(ws + W_E1B);
  short* we2b  = (short*)(ws + W_E2B);
  short* wd0b  = (short*)(ws + W_D0B);
  short* wd1b  = (short*)(ws + W_D1B);
  short* wd2b  = (short*)(ws + W_D2B);

  int B = 16;
  while (B > 1 && W_BYTES + (size_t)B*PER_IMG > ws_size) B >>= 1;

  char* act = ws + W_BYTES;
  size_t szA  = (size_t)B*16777216;
  size_t szBg = (size_t)B*8388608;
  size_t szC  = (size_t)B*4194304;
  bf16*  h0  = (bf16*) (act);
  bf16*  d2  = (bf16*) (act);
  bf16*  h1  = (bf16*) (act + szA);
  bf16*  d1  = (bf16*) (act + szA);
  bf16*  h2  = (bf16*) (act + szA + szBg);
  bf16*  d0  = (bf16*) (act + szA + szBg);
  bf16*  zqs = (bf16*) (act + szA + szBg + szC);

  auto nb = [](int total){ return dim3((unsigned)((total + 255) / 256)); };

  repack_tco<<<nb(128*3*16),  256, 0, stream>>>(enc_w0, wenc0, 128, 3, 16);
  repack_tco<<<nb(64*512*1),  256, 0, stream>>>(proj_w, wproj, 64, 512, 1);
  repack_cto<<<nb(3*128*9),   256, 0, stream>>>(out_w, wout, 3, 128, 9);
  repack_tcc_bf16<<<nb(256*128*16),256, 0, stream>>>(enc_w1, we1b, 256, 128);
  repack_tcc_bf16<<<nb(512*256*16),256, 0, stream>>>(enc_w2, we2b, 512, 256);
  repack_tcc_bf16<<<nb(512*64*16), 256, 0, stream>>>(dec_w0, wd0b, 512, 64);
  repack_tcc_bf16<<<nb(256*512*16),256, 0, stream>>>(dec_w1, wd1b, 256, 512);
  repack_tcc_bf16<<<nb(128*256*16),256, 0, stream>>>(dec_w2, wd2b, 128, 256);

  for (int n0 = 0; n0 < 16; n0 += B){
    const float* xc  = x      + (size_t)n0*3*65536;
    float* reconc    = recon  + (size_t)n0*3*65536;
    float* z_outc    = z_out  + (size_t)n0*65536;
    float* zq_outc   = zq_out + (size_t)n0*65536;

    // encoder
    conv_enc0<<<dim3(16,16,B), 256, 0, stream>>>(xc, wenc0, enc_b0, h0);
    conv_enc_mfma2<1><<<dim3(1, 64, 2*B), 256, 0, stream>>>(
        (const short*)h0, we1b, enc_b1, (short*)h1, 128, 128, 128, 256);
    conv_enc_mfma2<2><<<dim3(1, 16, 4*B), 256, 0, stream>>>(
        (const short*)h1, we2b, enc_b2, (short*)h2, 256, 64, 64, 512);
    conv1x1<8><<<dim3(4, 8, B), 256, 0, stream>>>(h2, wproj, proj_b, z_outc, 512, 1024, 64);

    vq_argmin<<<dim3(256*B), 256, 0, stream>>>(z_outc, cb, zq_outc, zqs);

    // decoder
    convT_mfma2<2><<<dim3(1, 16, 8*B), 256, 0, stream>>>(
        (const short*)zqs, wd0b, dec_b0, (short*)d0, 64, 32, 32, 512, 1);
    convT_mfma2<1><<<dim3(1, 64, 4*B), 256, 0, stream>>>(
        (const short*)d0, wd1b, dec_b1, (short*)d1, 512, 64, 64, 256, 1);
    convT_mfma2<1><<<dim3(2, 128, 2*B), 256, 0, stream>>>(
        (const short*)d1, wd2b, dec_b2, (short*)d2, 256, 128, 128, 128, 1);

    conv3x3_out2<<<dim3(64, B), 256, 0, stream>>>(d2, wout, out_b, reconc);
  }
}

// Round 9
// 3764.972 us; speedup vs baseline: 2.1131x; 2.1131x over previous
//
#include <hip/hip_runtime.h>
#include <hip/hip_bf16.h>

typedef __hip_bfloat16 bf16;
typedef __attribute__((ext_vector_type(8))) short short8;
typedef __attribute__((ext_vector_type(4))) short short4v;
typedef __attribute__((ext_vector_type(4))) float f32x4;

__device__ __forceinline__ bf16 f2b(float v){ return __float2bfloat16(v); }
__device__ __forceinline__ unsigned short bfbits(float v){
  union{ bf16 h; unsigned short u; } t; t.h = f2b(v); return t.u;
}
__device__ __forceinline__ float bs2f(short s){
  union{ unsigned u; float f; } t; t.u = ((unsigned)(unsigned short)s) << 16; return t.f;
}

// ---------------- weight repacks ----------------
// w[Cout][Cin][KK] f32 -> o[KK][Cin][Cout] f32  (enc0)
__global__ void repack_tco(const float* __restrict__ w, float* __restrict__ o,
                           int Cout, int Cin, int KK){
  int i = blockIdx.x*256 + threadIdx.x;
  int total = Cout*Cin*KK;
  if (i >= total) return;
  int co = i / (Cin*KK);
  int r  = i - co*(Cin*KK);
  int ci = r / KK;
  int t  = r - ci*KK;
  o[((size_t)t*Cin + ci)*Cout + co] = w[i];
}

// w[Cout][Cin][KK] f32 -> o[Cin][KK][Cout] f32  (out conv: [ci][tap][co])
__global__ void repack_cto(const float* __restrict__ w, float* __restrict__ o,
                           int Cout, int Cin, int KK){
  int i = blockIdx.x*256 + threadIdx.x;
  int total = Cout*Cin*KK;
  if (i >= total) return;
  int co = i / (Cin*KK);
  int r  = i - co*(Cin*KK);
  int ci = r / KK;
  int t  = r - ci*KK;
  o[((size_t)ci*KK + t)*Cout + co] = w[i];
}

// w[Cout][Cin][16] f32 -> o[tap][Cout][Cin] bf16  (MFMA A-operand)
__global__ void repack_tcc_bf16(const float* __restrict__ w, short* __restrict__ o,
                                int Cout, int Cin){
  int i = blockIdx.x*256 + threadIdx.x;
  int total = Cout*Cin*16;
  if (i >= total) return;
  int co = i / (Cin*16);
  int r  = i - co*(Cin*16);
  int ci = r >> 4;
  int t  = r & 15;
  o[((size_t)t*Cout + co)*Cin + ci] = (short)bfbits(w[i]);
}

// flat f32 -> bf16 (proj weights [co][ci])
__global__ void cvt_bf16(const float* __restrict__ w, short* __restrict__ o, int n){
  int i = blockIdx.x*256 + threadIdx.x;
  if (i < n) o[i] = (short)bfbits(w[i]);
}

// ---------------- enc0: conv k=4 s=2 p=1, NCHW f32 in -> NHWC bf16 out ----------------
__global__ __launch_bounds__(256) void conv_enc0(
    const float* __restrict__ x, const float* __restrict__ wp,  // [tap][ci][co]
    const float* __restrict__ bias, short* __restrict__ y)      // NHWC [128][128][128]
{
  int t = blockIdx.x*256 + threadIdx.x;
  int oh  = t >> 5;
  int ow0 = (t & 31) * 4;
  int co0 = blockIdx.y * 8;
  int n   = blockIdx.z;
  float acc[8][4];
  #pragma unroll
  for (int j=0;j<8;j++){
    float bv = bias[co0+j];
    #pragma unroll
    for (int o=0;o<4;o++) acc[j][o] = bv;
  }
  const float* xn = x + (size_t)n*3*65536;
  #pragma unroll
  for (int ci=0; ci<3; ci++){
    const float* xc = xn + (size_t)ci*65536;
    #pragma unroll
    for (int kh=0; kh<4; kh++){
      int ih = 2*oh - 1 + kh;
      float xv[12];
      if ((unsigned)ih < 256u){
        #pragma unroll
        for (int c2=0; c2<6; c2++){
          int col = 2*ow0 - 2 + 2*c2;
          if (col >= 0 && col < 256){
            float2 v = *(const float2*)(xc + (size_t)ih*256 + col);
            xv[2*c2] = v.x; xv[2*c2+1] = v.y;
          } else { xv[2*c2] = 0.f; xv[2*c2+1] = 0.f; }
        }
      } else {
        #pragma unroll
        for (int k=0;k<12;k++) xv[k] = 0.f;
      }
      #pragma unroll
      for (int kw=0; kw<4; kw++){
        const float* wr = wp + (size_t)((kh*4+kw)*3 + ci)*128 + co0;  // uniform
        #pragma unroll
        for (int j=0;j<8;j++){
          float wf = wr[j];
          #pragma unroll
          for (int o=0;o<4;o++)
            acc[j][o] = fmaf(xv[2*o+kw+1], wf, acc[j][o]);
        }
      }
    }
  }
  #pragma unroll
  for (int o=0;o<4;o++){
    short8 pk;
    #pragma unroll
    for (int j=0;j<8;j++) pk[j] = (short)bfbits(fmaxf(acc[j][o], 0.f));
    *(short8*)&y[(((size_t)n*128 + oh)*128 + (ow0+o))*128 + co0] = pk;
  }
}

// ---------------- enc1/enc2: conv k=4 s=2 p=1 MFMA, NHWC, 2cs x 2ss waves ----------------
template<int TS>
__global__ __launch_bounds__(256) void conv_enc_mfma(
    const short* __restrict__ x, const short* __restrict__ wb,
    const float* __restrict__ bias, short* __restrict__ y,
    int Cin, int Hin, int Win, int Cout)
{
  constexpr int SHW  = TS/32;
  constexpr int COB  = (4/SHW)*32;
  constexpr int CLS  = 2*TS + 2;
  constexpr int CIP  = 40;
  __shared__ __align__(16) short lds[4*CLS*CIP];

  int tid = threadIdx.x;
  int w = tid >> 6, lane = tid & 63;
  int sh = w % SHW, ch = w / SHW;
  int n15 = lane & 15, quad = lane >> 4;
  int oh = blockIdx.y;
  int j0 = blockIdx.x * TS;
  int nct = Cout / COB;
  int ct = blockIdx.z % nct;
  int nimg = blockIdx.z / nct;
  int co_base = ct*COB + ch*32;
  int Hout = Hin >> 1, Wout = Win >> 1;
  int row_org = 2*oh - 1;
  int col_org = 2*j0 - 1;

  f32x4 acc[2][2];
  #pragma unroll
  for (int cs=0; cs<2; cs++){
    int cb = co_base + cs*16 + quad*4;
    f32x4 bv = {bias[cb], bias[cb+1], bias[cb+2], bias[cb+3]};
    acc[cs][0] = bv; acc[cs][1] = bv;
  }

  const short* xn = x + (size_t)nimg*Hin*Win*Cin;
  for (int ci0 = 0; ci0 < Cin; ci0 += 32){
    __syncthreads();
    for (int idx = tid; idx < 4*CLS*4; idx += 256){
      int r   = idx / (CLS*4);
      int rem = idx - r*(CLS*4);
      int c   = rem >> 2;
      int q4  = rem & 3;
      int gi = row_org + r, gj = col_org + c;
      short8 v = {0,0,0,0,0,0,0,0};
      if ((unsigned)gi < (unsigned)Hin && (unsigned)gj < (unsigned)Win)
        v = *(const short8*)(xn + ((size_t)gi*Win + gj)*Cin + ci0 + q4*8);
      *(short8*)&lds[(r*CLS + c)*CIP + q4*8] = v;
    }
    __syncthreads();
    #pragma unroll
    for (int kh=0; kh<4; kh++){
      short8 bfr[4][2];
      #pragma unroll
      for (int kw=0; kw<4; kw++)
        #pragma unroll
        for (int ss=0; ss<2; ss++){
          int col = 2*(sh*32 + ss*16 + n15) + kw;
          bfr[kw][ss] = *(const short8*)&lds[(kh*CLS + col)*CIP + quad*8];
        }
      #pragma unroll
      for (int kw=0; kw<4; kw++){
        int tap = kh*4 + kw;
        #pragma unroll
        for (int cs=0; cs<2; cs++){
          short8 af = *(const short8*)(wb +
              (size_t)(tap*Cout + co_base + cs*16 + n15)*Cin + ci0 + quad*8);
          #pragma unroll
          for (int ss=0; ss<2; ss++)
            acc[cs][ss] = __builtin_amdgcn_mfma_f32_16x16x32_bf16(af, bfr[kw][ss], acc[cs][ss], 0,0,0);
        }
      }
    }
  }
  #pragma unroll
  for (int cs=0; cs<2; cs++)
    #pragma unroll
    for (int ss=0; ss<2; ss++){
      int jj = j0 + sh*32 + ss*16 + n15;
      short4v pk;
      #pragma unroll
      for (int r=0;r<4;r++) pk[r] = (short)bfbits(fmaxf(acc[cs][ss][r], 0.f));
      *(short4v*)&y[(((size_t)nimg*Hout + oh)*Wout + jj)*Cout + co_base + cs*16 + quad*4] = pk;
    }
}

// ---------------- proj: 1x1 conv as MFMA GEMM; z -> NCHW f32 (d_out) + NHWC f32 (ws) ----------------
__global__ __launch_bounds__(256) void proj_mfma(
    const short* __restrict__ x, const short* __restrict__ wb,   // x NHWC [1024][512]; wb [64co][512ci]
    const float* __restrict__ bias, float* __restrict__ z_nchw,
    float* __restrict__ z_nhwc)
{
  int tid = threadIdx.x;
  int w = tid >> 6, lane = tid & 63;
  int n15 = lane & 15, quad = lane >> 4;
  int sp0 = blockIdx.x*64 + w*16;
  int nimg = blockIdx.y;
  f32x4 acc[4];
  #pragma unroll
  for (int cs=0; cs<4; cs++){
    int cb = cs*16 + quad*4;
    acc[cs] = f32x4{bias[cb], bias[cb+1], bias[cb+2], bias[cb+3]};
  }
  const short* xs = x + ((size_t)nimg*1024 + sp0 + n15)*512;
  for (int ci0=0; ci0<512; ci0+=32){
    short8 bfr = *(const short8*)(xs + ci0 + quad*8);
    #pragma unroll
    for (int cs=0; cs<4; cs++){
      short8 af = *(const short8*)(wb + (size_t)(cs*16+n15)*512 + ci0 + quad*8);
      acc[cs] = __builtin_amdgcn_mfma_f32_16x16x32_bf16(af, bfr, acc[cs], 0,0,0);
    }
  }
  int sp = sp0 + n15;
  #pragma unroll
  for (int cs=0; cs<4; cs++){
    #pragma unroll
    for (int r=0;r<4;r++)
      z_nchw[(size_t)nimg*65536 + (size_t)(cs*16+quad*4+r)*1024 + sp] = acc[cs][r];
    *(f32x4*)&z_nhwc[((size_t)nimg*1024 + sp)*64 + cs*16 + quad*4] = acc[cs];
  }
}

// ---------------- VQ: per-wave argmin over 1024 codes (NHWC z) ----------------
__global__ void vq_argmin(const float* __restrict__ zf, const float* __restrict__ cbf,
                          float* __restrict__ zq, short* __restrict__ zqst)
{
  __shared__ float lz[4][64];
  int t = threadIdx.x;
  int q = t >> 6, l = t & 63;
  int p = blockIdx.x*4 + q;
  int n = p >> 10, hw = p & 1023;
  size_t nhbase = ((size_t)n*1024 + hw)*64;
  float zl = zf[nhbase + l];
  lz[q][l] = zl;
  __syncthreads();
  float best = 3.0e38f; int bi = 0;
  const float* zv = &lz[q][0];
  for (int c = l; c < 1024; c += 64){
    const float4* row = reinterpret_cast<const float4*>(cbf + (size_t)c*64);
    float d = 0.f;
    #pragma unroll
    for (int v4 = 0; v4 < 16; v4++){
      float4 cv = row[v4];
      int j0 = v4*4;
      float d0 = zv[j0+0]-cv.x; d = fmaf(d0,d0,d);
      float d1 = zv[j0+1]-cv.y; d = fmaf(d1,d1,d);
      float d2 = zv[j0+2]-cv.z; d = fmaf(d2,d2,d);
      float d3 = zv[j0+3]-cv.w; d = fmaf(d3,d3,d);
    }
    if (d < best){ best = d; bi = c; }
  }
  #pragma unroll
  for (int off = 32; off > 0; off >>= 1){
    float od = __shfl_down(best, off, 64);
    int   oi = __shfl_down(bi,  off, 64);
    if (od < best || (od == best && oi < bi)){ best = od; bi = oi; }
  }
  bi = __shfl(bi, 0, 64);
  float qv = cbf[(size_t)bi*64 + l];
  zq[(size_t)n*65536 + (size_t)l*1024 + hw] = qv;
  zqst[nhbase + l] = (short)bfbits(zl + (qv - zl));
}

// ---------------- decoder: convT k=4 s=2 MFMA, NHWC, 2cs x 2ss waves ----------------
template<int TS>
__global__ __launch_bounds__(256) void convT_mfma(
    const short* __restrict__ x, const short* __restrict__ wb,
    const float* __restrict__ bias, short* __restrict__ y,
    int Cin, int Hin, int Win, int Cout, int relu)
{
  constexpr int SHW  = TS/32;
  constexpr int COB  = (4/SHW)*32;
  constexpr int CLS  = TS + 2;
  constexpr int CIP  = 40;
  __shared__ __align__(16) short lds[3*CLS*CIP];

  int tid = threadIdx.x;
  int w = tid >> 6, lane = tid & 63;
  int sh = w % SHW, ch = w / SHW;
  int n15 = lane & 15, quad = lane >> 4;
  int i0 = blockIdx.y;
  int j0 = blockIdx.x * TS;
  int nct = Cout / COB;
  int ct = blockIdx.z % nct;
  int nimg = blockIdx.z / nct;
  int co_base = ct*COB + ch*32;

  f32x4 acc[2][2][4];
  #pragma unroll
  for (int cs=0; cs<2; cs++){
    int cb = co_base + cs*16 + quad*4;
    f32x4 bv = {bias[cb], bias[cb+1], bias[cb+2], bias[cb+3]};
    #pragma unroll
    for (int ss=0; ss<2; ss++)
      #pragma unroll
      for (int p=0;p<4;p++) acc[cs][ss][p] = bv;
  }

  const short* xn = x + (size_t)nimg*Hin*Win*Cin;
  for (int ci0 = 0; ci0 < Cin; ci0 += 32){
    __syncthreads();
    for (int idx = tid; idx < 3*CLS*4; idx += 256){
      int r   = idx / (CLS*4);
      int rem = idx - r*(CLS*4);
      int c   = rem >> 2;
      int q4  = rem & 3;
      int gi = i0 - 1 + r, gj = j0 - 1 + c;
      short8 v = {0,0,0,0,0,0,0,0};
      if ((unsigned)gi < (unsigned)Hin && (unsigned)gj < (unsigned)Win)
        v = *(const short8*)(xn + ((size_t)gi*Win + gj)*Cin + ci0 + q4*8);
      *(short8*)&lds[(r*CLS + c)*CIP + q4*8] = v;
    }
    __syncthreads();
    short8 bfr[9][2];
    #pragma unroll
    for (int dr=0; dr<3; dr++)
      #pragma unroll
      for (int dc=0; dc<3; dc++)
        #pragma unroll
        for (int ss=0; ss<2; ss++){
          int col = sh*32 + ss*16 + n15 + dc;
          bfr[dr*3+dc][ss] = *(const short8*)&lds[(dr*CLS + col)*CIP + quad*8];
        }
    #pragma unroll
    for (int ph=0; ph<2; ph++)
      #pragma unroll
      for (int pw=0; pw<2; pw++){
        int p = ph*2 + pw;
        #pragma unroll
        for (int u=0; u<2; u++)
          #pragma unroll
          for (int v=0; v<2; v++){
            int tap  = (ph + 2*u)*4 + (pw + 2*v);
            int sidx = (u + ph)*3 + (v + pw);
            #pragma unroll
            for (int cs=0; cs<2; cs++){
              short8 af = *(const short8*)(wb +
                  (size_t)(tap*Cout + co_base + cs*16 + n15)*Cin + ci0 + quad*8);
              #pragma unroll
              for (int ss=0; ss<2; ss++)
                acc[cs][ss][p] = __builtin_amdgcn_mfma_f32_16x16x32_bf16(af, bfr[sidx][ss], acc[cs][ss][p], 0,0,0);
            }
          }
      }
  }
  int Hout = Hin*2, Wout = Win*2;
  #pragma unroll
  for (int cs=0; cs<2; cs++)
    #pragma unroll
    for (int ss=0; ss<2; ss++){
      int jj = j0 + sh*32 + ss*16 + n15;
      #pragma unroll
      for (int ph=0; ph<2; ph++)
        #pragma unroll
        for (int pw=0; pw<2; pw++){
          short4v pk;
          #pragma unroll
          for (int r=0;r<4;r++){
            float v2 = acc[cs][ss][ph*2+pw][r];
            if (relu) v2 = fmaxf(v2, 0.f);
            pk[r] = (short)bfbits(v2);
          }
          *(short4v*)&y[(((size_t)nimg*Hout + 2*i0+ph)*Wout + 2*jj+pw)*Cout + co_base + cs*16 + quad*4] = pk;
        }
    }
}

// ---------------- out conv: 3x3 p=1 s=1, NHWC in -> NCHW f32 out ----------------
__global__ __launch_bounds__(256) void conv3x3_out3(
    const short* __restrict__ x, const float* __restrict__ wct,  // [ci][9][3]
    const float* __restrict__ bias, float* __restrict__ y)
{
  __shared__ __align__(16) short xl[6*66*16];
  int tid = threadIdx.x;
  int row = tid >> 6;
  int col = tid & 63;
  int j0 = blockIdx.x*64;
  int r0 = blockIdx.y*4;
  int n  = blockIdx.z;
  const short* xn = x + (size_t)n*65536*128;
  float acc[3] = {bias[0], bias[1], bias[2]};
  for (int g=0; g<8; g++){
    int cig = g*16;
    __syncthreads();
    for (int idx = tid; idx < 792; idx += 256){
      int r = idx / 132;
      int rem = idx - r*132;
      int c = rem >> 1;
      int h = rem & 1;
      int gi = r0 - 1 + r, gj = j0 - 1 + c;
      short8 v = {0,0,0,0,0,0,0,0};
      if ((unsigned)gi < 256u && (unsigned)gj < 256u)
        v = *(const short8*)(xn + ((size_t)gi*256 + gj)*128 + cig + h*8);
      *(short8*)&xl[(r*66 + c)*16 + h*8] = v;
    }
    __syncthreads();
    #pragma unroll
    for (int half=0; half<2; half++){
      short8 xv[9];
      #pragma unroll
      for (int dr=0; dr<3; dr++)
        #pragma unroll
        for (int dc=0; dc<3; dc++)
          xv[dr*3+dc] = *(const short8*)&xl[((row+dr)*66 + col+dc)*16 + half*8];
      #pragma unroll
      for (int k=0;k<8;k++){
        const float* wr = wct + (size_t)(cig + half*8 + k)*27;   // uniform
        #pragma unroll
        for (int tp=0; tp<9; tp++){
          float xf = bs2f(xv[tp][k]);
          acc[0] = fmaf(xf, wr[tp*3+0], acc[0]);
          acc[1] = fmaf(xf, wr[tp*3+1], acc[1]);
          acc[2] = fmaf(xf, wr[tp*3+2], acc[2]);
        }
      }
    }
  }
  size_t obase = (size_t)n*3*65536 + (size_t)(r0+row)*256 + j0 + col;
  y[obase]          = acc[0];
  y[obase + 65536]  = acc[1];
  y[obase + 131072] = acc[2];
}

// ---------------- workspace layout (bytes) ----------------
static const size_t W_WENC0  = 0;           //  24,576 f32 [tap][ci][co]
static const size_t W_WPROJB = 24576;       //  65,536 bf16 [co][ci]
static const size_t W_WOUT   = 90112;       //  13,824 f32 [ci][tap][co]
static const size_t W_E1B    = 103936;      //  1,048,576 bf16 [tap][co][ci]
static const size_t W_E2B    = 1152512;     //  4,194,304
static const size_t W_D0B    = 5346816;     //  1,048,576
static const size_t W_D1B    = 6395392;     //  4,194,304
static const size_t W_D2B    = 10589696;    //  1,048,576
static const size_t W_BYTES  = 11638272;
// per-image activations (NHWC, lifetime-aliased):
//   A 16MiB (h0 4M / d2 16M), Bg 8MiB (h1 2M / d1 8M), C 4MiB (h2 1M / d0 4M),
//   zf f32 256K, zqs bf16 128K
static const size_t PER_IMG = 29753344;

extern "C" void kernel_launch(void* const* d_in, const int* in_sizes, int n_in,
                              void* d_out, int out_size, void* d_ws, size_t ws_size,
                              hipStream_t stream)
{
  const float* x      = (const float*)d_in[0];
  const float* enc_w0 = (const float*)d_in[1];
  const float* enc_b0 = (const float*)d_in[2];
  const float* enc_w1 = (const float*)d_in[3];
  const float* enc_b1 = (const float*)d_in[4];
  const float* enc_w2 = (const float*)d_in[5];
  const float* enc_b2 = (const float*)d_in[6];
  const float* proj_w = (const float*)d_in[7];
  const float* proj_b = (const float*)d_in[8];
  const float* dec_w0 = (const float*)d_in[9];
  const float* dec_b0 = (const float*)d_in[10];
  const float* dec_w1 = (const float*)d_in[11];
  const float* dec_b1 = (const float*)d_in[12];
  const float* dec_w2 = (const float*)d_in[13];
  const float* dec_b2 = (const float*)d_in[14];
  const float* out_w  = (const float*)d_in[15];
  const float* out_b  = (const float*)d_in[16];
  const float* cb     = (const float*)d_in[17];

  float* out    = (float*)d_out;
  float* recon  = out;
  float* z_out  = out + 3145728;
  float* zq_out = out + 4194304;

  char* ws = (char*)d_ws;
  float* wenc0  = (float*)(ws + W_WENC0);
  short* wprojb = (short*)(ws + W_WPROJB);
  float* wout   = (float*)(ws + W_WOUT);
  short* we1b   = (short*)(ws + W_E1B);
  short* we2b   = (short*)(ws + W_E2B);
  short* wd0b   = (short*)(ws + W_D0B);
  short* wd1b   = (short*)(ws + W_D1B);
  short* wd2b   = (short*)(ws + W_D2B);

  int B = 16;
  while (B > 1 && W_BYTES + (size_t)B*PER_IMG > ws_size) B >>= 1;

  char* act = ws + W_BYTES;
  size_t szA  = (size_t)B*16777216;
  size_t szBg = (size_t)B*8388608;
  size_t szC  = (size_t)B*4194304;
  short* h0  = (short*)(act);
  short* d2  = (short*)(act);
  short* h1  = (short*)(act + szA);
  short* d1  = (short*)(act + szA);
  short* h2  = (short*)(act + szA + szBg);
  short* d0  = (short*)(act + szA + szBg);
  float* zf  = (float*)(act + szA + szBg + szC);
  short* zqs = (short*)(act + szA + szBg + szC + (size_t)B*262144);

  auto nb = [](int total){ return dim3((unsigned)((total + 255) / 256)); };

  repack_tco<<<nb(128*3*16),  256, 0, stream>>>(enc_w0, wenc0, 128, 3, 16);
  cvt_bf16<<<nb(32768),       256, 0, stream>>>(proj_w, wprojb, 32768);
  repack_cto<<<nb(3*128*9),   256, 0, stream>>>(out_w, wout, 3, 128, 9);
  repack_tcc_bf16<<<nb(256*128*16),256, 0, stream>>>(enc_w1, we1b, 256, 128);
  repack_tcc_bf16<<<nb(512*256*16),256, 0, stream>>>(enc_w2, we2b, 512, 256);
  repack_tcc_bf16<<<nb(512*64*16), 256, 0, stream>>>(dec_w0, wd0b, 512, 64);
  repack_tcc_bf16<<<nb(256*512*16),256, 0, stream>>>(dec_w1, wd1b, 256, 512);
  repack_tcc_bf16<<<nb(128*256*16),256, 0, stream>>>(dec_w2, wd2b, 128, 256);

  for (int n0 = 0; n0 < 16; n0 += B){
    const float* xc  = x      + (size_t)n0*3*65536;
    float* reconc    = recon  + (size_t)n0*3*65536;
    float* z_outc    = z_out  + (size_t)n0*65536;
    float* zq_outc   = zq_out + (size_t)n0*65536;

    // encoder (NHWC activations)
    conv_enc0<<<dim3(16,16,B), 256, 0, stream>>>(xc, wenc0, enc_b0, h0);
    conv_enc_mfma<64><<<dim3(1, 64, B*4), 256, 0, stream>>>(
        h0, we1b, enc_b1, h1, 128, 128, 128, 256);
    conv_enc_mfma<32><<<dim3(1, 32, B*4), 256, 0, stream>>>(
        h1, we2b, enc_b2, h2, 256, 64, 64, 512);
    proj_mfma<<<dim3(16, B), 256, 0, stream>>>(h2, wprojb, proj_b, z_outc, zf);

    vq_argmin<<<dim3(256*B), 256, 0, stream>>>(zf, cb, zq_outc, zqs);

    // decoder (NHWC)
    convT_mfma<32><<<dim3(1, 32, B*4), 256, 0, stream>>>(
        zqs, wd0b, dec_b0, d0, 64, 32, 32, 512, 1);
    convT_mfma<64><<<dim3(1, 64, B*4), 256, 0, stream>>>(
        d0, wd1b, dec_b1, d1, 512, 64, 64, 256, 1);
    convT_mfma<64><<<dim3(2, 128, B*2), 256, 0, stream>>>(
        d1, wd2b, dec_b2, d2, 256, 128, 128, 128, 1);

    conv3x3_out3<<<dim3(4, 64, B), 256, 0, stream>>>(d2, wout, out_b, reconc);
  }
}